// Round 1
// 550.137 us; speedup vs baseline: 1.0317x; 1.0317x over previous
//
#include <hip/hip_runtime.h>
#include <math.h>

#define NN 20000
#define NE 320000
#define IN_DIM 16
#define HID 64
#define HEADS 4
#define HD 256          // HEADS*HID
#define OUTW 208        // 16 + 3*64
#define NEG 0.2f

typedef unsigned short u16;
typedef unsigned int u32;
typedef __attribute__((ext_vector_type(8))) short bf16x8;   // MFMA A/B frag
typedef __attribute__((ext_vector_type(8))) unsigned short u16x8;
typedef __attribute__((ext_vector_type(4))) float f32x4;    // MFMA C/D frag

__device__ __forceinline__ float b2f(u16 u) {
  union { u32 i; float f; } c; c.i = ((u32)u) << 16; return c.f;
}
__device__ __forceinline__ u16 f2b(float f) {
  union { float f; u32 i; } c; c.f = f;
  u32 r = (c.i + 0x7FFFu + ((c.i >> 16) & 1u)) >> 16;
  return (u16)r;
}

// ---------------- embed: feat = node_feat @ W_embed + b; also write out cols 0..79
__global__ void k_embed(const float* __restrict__ nf, const float* __restrict__ We,
                        const float* __restrict__ be, float* __restrict__ feat,
                        float* __restrict__ out) {
  int tid = blockIdx.x * blockDim.x + threadIdx.x;   // NN*64 threads
  int n = tid >> 6, c = tid & 63;
  if (n >= NN) return;
  float acc = be[c];
#pragma unroll
  for (int k = 0; k < IN_DIM; ++k)
    acc += nf[n * IN_DIM + k] * We[k * HID + c];
  feat[n * HID + c] = acc;
  out[n * OUTW + 16 + c] = acc;
  if (c < IN_DIM) out[n * OUTW + c] = nf[n * IN_DIM + c];
}

// ---------------- CSR build over dst
__global__ void k_count(const int* __restrict__ dst, int* __restrict__ counts) {
  int e = blockIdx.x * blockDim.x + threadIdx.x;
  if (e < NE) atomicAdd(&counts[dst[e]], 1);
}

// single block, 1024 threads, shuffle-based scan
__global__ void k_scan(const int* __restrict__ counts, int* __restrict__ rowptr) {
  __shared__ int wsum[16];
  __shared__ int tot;
  int lane = threadIdx.x & 63, wid = threadIdx.x >> 6;
  int running = 0;
  if (threadIdx.x == 0) rowptr[0] = 0;
  for (int base = 0; base < NN; base += 1024) {
    int i = base + threadIdx.x;
    int x = (i < NN) ? counts[i] : 0;
#pragma unroll
    for (int d = 1; d < 64; d <<= 1) {
      int t = __shfl_up(x, d);
      if (lane >= d) x += t;
    }
    if (lane == 63) wsum[wid] = x;
    __syncthreads();
    if (wid == 0) {
      int wv = (lane < 16) ? wsum[lane] : 0;
#pragma unroll
      for (int d = 1; d < 16; d <<= 1) {
        int t = __shfl_up(wv, d);
        if (lane >= d) wv += t;
      }
      if (lane < 16) wsum[lane] = wv;
      if (lane == 15) tot = wv;
    }
    __syncthreads();
    int wpre = (wid == 0) ? 0 : wsum[wid - 1];
    if (i < NN) rowptr[i + 1] = running + wpre + x;
    running += tot;
    __syncthreads();
  }
}

// scatter: eidx (CSR slot -> original edge), src/dst permuted into CSR order
__global__ void k_scatter(const int* __restrict__ dst, const int* __restrict__ src,
                          const int* __restrict__ rowptr, int* __restrict__ cursor,
                          int* __restrict__ eidx, int* __restrict__ srcp,
                          int* __restrict__ dstp) {
  int e = blockIdx.x * blockDim.x + threadIdx.x;
  if (e >= NE) return;
  int d = dst[e];
  int pos = rowptr[d] + atomicAdd(&cursor[d], 1);
  eidx[pos] = e;
  srcp[pos] = src[e];
  dstp[pos] = d;
}

// ---------------- permute+convert edge_feat into CSR slot order (bf16).
// Replaces k_convert. Done ONCE; kills the eidx->efb dependent gather chain in
// k_edgelogits for BOTH layers (edge_feat is layer-invariant).
__global__ void k_permute(const float* __restrict__ ef, const int* __restrict__ eidx,
                          u16* __restrict__ efbp) {
  int t = blockIdx.x * blockDim.x + threadIdx.x;   // NE*16 threads
  int slot = t >> 4, c = (t & 15) * 4;
  int e = eidx[slot];                               // broadcast per 16 lanes
  float4 v = *reinterpret_cast<const float4*>(&ef[(size_t)e * HID + c]);
  ushort4 o;
  o.x = f2b(v.x); o.y = f2b(v.y); o.z = f2b(v.z); o.w = f2b(v.w);
  *reinterpret_cast<ushort4*>(&efbp[(size_t)slot * HID + c]) = o;
}

// ---------------- transpose + bf16-convert W_fij: Wt[n][k] = Wf[k][n]
__global__ void k_prepw(const float* __restrict__ Wf, u16* __restrict__ Wt) {
  int tid = blockIdx.x * blockDim.x + threadIdx.x;   // HID*HD threads
  int n = tid >> 6, k = tid & 63;
  if (n >= HD) return;
  Wt[n * HID + k] = f2b(Wf[k * HD + n]);
}

// ---------------- node projections: fni (+b_att folded), fnj, hn -> bf16 (8/block)
__global__ __launch_bounds__(256) void k_nodeproj(
    const float* __restrict__ feat, const float* __restrict__ Wni,
    const float* __restrict__ Wnj, const float* __restrict__ Wnd,
    const float* __restrict__ batt, u16* __restrict__ fni,
    u16* __restrict__ fnj, u16* __restrict__ hn) {
  __shared__ float hs[8 * HID];
  int n0 = blockIdx.x * 8;
  int c = threadIdx.x;
  for (int i = threadIdx.x; i < 8 * HID; i += 256)
    hs[i] = feat[(size_t)(n0 + (i >> 6)) * HID + (i & 63)];
  __syncthreads();
  float aI[8] = {0}, aJ[8] = {0}, aN[8] = {0};
  for (int k = 0; k < HID; ++k) {
    float wi = Wni[k * HD + c], wj = Wnj[k * HD + c], wn = Wnd[k * HD + c];
#pragma unroll
    for (int t = 0; t < 8; ++t) {
      float x = hs[t * HID + k];
      aI[t] += x * wi; aJ[t] += x * wj; aN[t] += x * wn;
    }
  }
  float b = batt[c];
#pragma unroll
  for (int t = 0; t < 8; ++t) {
    int n = n0 + t;
    fni[(size_t)n * HD + c] = f2b(aI[t] + b);
    fnj[(size_t)n * HD + c] = f2b(aJ[t]);
    hn[(size_t)n * HD + c]  = f2b(aN[t]);
  }
}

// ---------------- edge logits via MFMA over CSR slots, 2-tile ILP
// efbp is pre-permuted to CSR order: coalesced streaming A-frag loads, no eidx.
// fni/fnj gathers widened to 16B/lane (8 lanes per 128B head-slice): half the
// gather instruction count vs ushort4, same register bytes.
// elog head-major: elog[h*NE + slot]
__global__ __launch_bounds__(256) void k_edgelogits(
    const u16* __restrict__ efbp, const int* __restrict__ srcp,
    const int* __restrict__ dstp, const u16* __restrict__ fni,
    const u16* __restrict__ fnj, const u16* __restrict__ Wt,
    const float* __restrict__ attnL, float* __restrict__ elog) {
  __shared__ float gb[HEADS][16][68];   // per-wave slice, +4 pad
  int h = threadIdx.x >> 6;            // wave = head
  int l = threadIdx.x & 63;
  int q = l >> 4;                      // quad
  int n = l & 15;
  int e0 = l >> 3;                     // 0..7: local edge within half-tile
  int cb = (l & 7) * 8;                // element offset within 64-wide head slice
  bf16x8 bfr[4][2];
#pragma unroll
  for (int nt = 0; nt < 4; ++nt)
#pragma unroll
    for (int kk = 0; kk < 2; ++kk)
      bfr[nt][kk] = *reinterpret_cast<const bf16x8*>(
          &Wt[(h * 64 + nt * 16 + n) * HID + kk * 32 + q * 8]);
  float at[4];
#pragma unroll
  for (int nt = 0; nt < 4; ++nt) at[nt] = attnL[h * 64 + nt * 16 + n];

#define COMMIT(av, bv, row)                                           \
  {                                                                   \
    float4 g0, g1;                                                    \
    g0.x = b2f(av[0]) + b2f(bv[0]); g0.y = b2f(av[1]) + b2f(bv[1]);   \
    g0.z = b2f(av[2]) + b2f(bv[2]); g0.w = b2f(av[3]) + b2f(bv[3]);   \
    g1.x = b2f(av[4]) + b2f(bv[4]); g1.y = b2f(av[5]) + b2f(bv[5]);   \
    g1.z = b2f(av[6]) + b2f(bv[6]); g1.w = b2f(av[7]) + b2f(bv[7]);   \
    *reinterpret_cast<float4*>(&gb[h][row][cb]) = g0;                 \
    *reinterpret_cast<float4*>(&gb[h][row][cb + 4]) = g1;             \
  }

#define TILEMMA(aa0, aa1, ibase)                                                  \
  {                                                                               \
    float sumr[4] = {0.f, 0.f, 0.f, 0.f};                                         \
    _Pragma("unroll")                                                             \
    for (int nt = 0; nt < 4; ++nt) {                                              \
      f32x4 acc = {0.f, 0.f, 0.f, 0.f};                                           \
      acc = __builtin_amdgcn_mfma_f32_16x16x32_bf16(aa0, bfr[nt][0], acc, 0, 0, 0); \
      acc = __builtin_amdgcn_mfma_f32_16x16x32_bf16(aa1, bfr[nt][1], acc, 0, 0, 0); \
      _Pragma("unroll")                                                           \
      for (int r = 0; r < 4; ++r) {                                               \
        float v = acc[r] + gb[h][q * 4 + r][nt * 16 + n];                         \
        v = v > 0.f ? v : NEG * v;                                                \
        sumr[r] += v * at[nt];                                                    \
      }                                                                           \
    }                                                                             \
    _Pragma("unroll")                                                             \
    for (int r = 0; r < 4; ++r) {                                                 \
      float v = sumr[r];                                                          \
      v += __shfl_xor(v, 1);                                                      \
      v += __shfl_xor(v, 2);                                                      \
      v += __shfl_xor(v, 4);                                                      \
      v += __shfl_xor(v, 8);                                                      \
      if (n == 0) elog[(size_t)h * NE + (ibase) + q * 4 + r] = v;                 \
    }                                                                             \
  }

  const int NT = NE / 16;  // 20000 tiles
  const int G = gridDim.x;
  for (int tile = blockIdx.x; tile < NT; tile += 2 * G) {
    int t1 = tile + G;
    // ---- issue ALL loads for both tiles (2x memory-level parallelism)
    int i0 = tile * 16;
    bf16x8 a00 = *reinterpret_cast<const bf16x8*>(&efbp[(size_t)(i0 + n) * HID + q * 8]);
    bf16x8 a01 = *reinterpret_cast<const bf16x8*>(&efbp[(size_t)(i0 + n) * HID + 32 + q * 8]);
    int sA0 = srcp[i0 + e0],     dA0 = dstp[i0 + e0];
    int sA1 = srcp[i0 + 8 + e0], dA1 = dstp[i0 + 8 + e0];
    u16x8 avA0 = *reinterpret_cast<const u16x8*>(&fni[(size_t)sA0 * HD + h * 64 + cb]);
    u16x8 bvA0 = *reinterpret_cast<const u16x8*>(&fnj[(size_t)dA0 * HD + h * 64 + cb]);
    u16x8 avA1 = *reinterpret_cast<const u16x8*>(&fni[(size_t)sA1 * HD + h * 64 + cb]);
    u16x8 bvA1 = *reinterpret_cast<const u16x8*>(&fnj[(size_t)dA1 * HD + h * 64 + cb]);
    int i1 = 0;
    bf16x8 a10 = {}, a11 = {};
    u16x8 avB0 = {}, bvB0 = {}, avB1 = {}, bvB1 = {};
    bool has1 = (t1 < NT);
    if (has1) {
      i1 = t1 * 16;
      a10 = *reinterpret_cast<const bf16x8*>(&efbp[(size_t)(i1 + n) * HID + q * 8]);
      a11 = *reinterpret_cast<const bf16x8*>(&efbp[(size_t)(i1 + n) * HID + 32 + q * 8]);
      int sB0 = srcp[i1 + e0],     dB0 = dstp[i1 + e0];
      int sB1 = srcp[i1 + 8 + e0], dB1 = dstp[i1 + 8 + e0];
      avB0 = *reinterpret_cast<const u16x8*>(&fni[(size_t)sB0 * HD + h * 64 + cb]);
      bvB0 = *reinterpret_cast<const u16x8*>(&fnj[(size_t)dB0 * HD + h * 64 + cb]);
      avB1 = *reinterpret_cast<const u16x8*>(&fni[(size_t)sB1 * HD + h * 64 + cb]);
      bvB1 = *reinterpret_cast<const u16x8*>(&fnj[(size_t)dB1 * HD + h * 64 + cb]);
    }
    // ---- tile 0: commit to wave-private LDS, MFMA, epilogue
    COMMIT(avA0, bvA0, e0);
    COMMIT(avA1, bvA1, 8 + e0);
    TILEMMA(a00, a01, i0);
    // ---- tile 1 (same LDS slice, wave-private reuse)
    if (has1) {
      COMMIT(avB0, bvB0, e0);
      COMMIT(avB1, bvB1, 8 + e0);
      TILEMMA(a10, a11, i1);
    }
  }
#undef COMMIT
#undef TILEMMA
}

// ---------------- aggregation: one wave per node; softmax stats computed
// in-wave (k_mz fused): 16 lanes per head do a strided max/sum over the row.
__global__ __launch_bounds__(256) void k_agg(
    const int* __restrict__ rowptr, const int* __restrict__ srcp,
    const float* __restrict__ elog, const u16* __restrict__ hn,
    float* __restrict__ agg) {
  int n = (blockIdx.x * blockDim.x + threadIdx.x) >> 6;
  int j = threadIdx.x & 63;
  if (n >= NN) return;
  int s0 = rowptr[n], s1 = rowptr[n + 1];
  int h = j >> 4, u = j & 15;
  const float* er = elog + (size_t)h * NE;
  // --- fused m/z: strided over the row, reduce within the 16-lane head group
  float m = -1e30f;
  for (int i = s0 + u; i < s1; i += 16) m = fmaxf(m, er[i]);
  m = fmaxf(m, __shfl_xor(m, 1));
  m = fmaxf(m, __shfl_xor(m, 2));
  m = fmaxf(m, __shfl_xor(m, 4));
  m = fmaxf(m, __shfl_xor(m, 8));
  float z = 0.f;
  for (int i = s0 + u; i < s1; i += 16) z += __expf(er[i] - m);
  z += __shfl_xor(z, 1);
  z += __shfl_xor(z, 2);
  z += __shfl_xor(z, 4);
  z += __shfl_xor(z, 8);
  float invz = (z > 0.f) ? 1.0f / z : 0.f;
  // --- weighted aggregation
  float4 ac[8];
#pragma unroll
  for (int t = 0; t < 8; ++t) ac[t] = make_float4(0, 0, 0, 0);
  int i = s0;
  for (; i + 8 <= s1; i += 8) {
    int sv[8]; float wv[8]; ushort4 vv[8];
#pragma unroll
    for (int t = 0; t < 8; ++t) sv[t] = srcp[i + t];
#pragma unroll
    for (int t = 0; t < 8; ++t) wv[t] = __expf(er[i + t] - m) * invz;
#pragma unroll
    for (int t = 0; t < 8; ++t)
      vv[t] = *reinterpret_cast<const ushort4*>(&hn[(size_t)sv[t] * HD + 4 * j]);
#pragma unroll
    for (int t = 0; t < 8; ++t) {
      ac[t].x += b2f(vv[t].x) * wv[t]; ac[t].y += b2f(vv[t].y) * wv[t];
      ac[t].z += b2f(vv[t].z) * wv[t]; ac[t].w += b2f(vv[t].w) * wv[t];
    }
  }
  for (; i < s1; ++i) {
    int s = srcp[i];
    float w = __expf(er[i] - m) * invz;
    ushort4 v = *reinterpret_cast<const ushort4*>(&hn[(size_t)s * HD + 4 * j]);
    ac[0].x += b2f(v.x) * w; ac[0].y += b2f(v.y) * w;
    ac[0].z += b2f(v.z) * w; ac[0].w += b2f(v.w) * w;
  }
  float4 acc;
  acc.x = ((ac[0].x + ac[1].x) + (ac[2].x + ac[3].x)) + ((ac[4].x + ac[5].x) + (ac[6].x + ac[7].x));
  acc.y = ((ac[0].y + ac[1].y) + (ac[2].y + ac[3].y)) + ((ac[4].y + ac[5].y) + (ac[6].y + ac[7].y));
  acc.z = ((ac[0].z + ac[1].z) + (ac[2].z + ac[3].z)) + ((ac[4].z + ac[5].z) + (ac[6].z + ac[7].z));
  acc.w = ((ac[0].w + ac[1].w) + (ac[2].w + ac[3].w)) + ((ac[4].w + ac[5].w) + (ac[6].w + ac[7].w));
  *reinterpret_cast<float4*>(&agg[(size_t)n * HD + 4 * j]) = acc;
}

// ---------------- MLP + residual: feat = agg @ W_mlp + b + feat; write out slice
__global__ __launch_bounds__(256) void k_mlp(
    const float* __restrict__ agg, const float* __restrict__ Wm,
    const float* __restrict__ bm, float* __restrict__ feat,
    float* __restrict__ out, int outoff) {
  __shared__ float as_[32 * HD];
  int n0 = blockIdx.x * 32;
  for (int i = threadIdx.x; i < 32 * HD; i += 256) as_[i] = agg[(size_t)n0 * HD + i];
  __syncthreads();
  int c = threadIdx.x & 63;
  int g = threadIdx.x >> 6;
  float acc[8] = {0};
  for (int k = 0; k < HD; ++k) {
    float wv = Wm[k * HID + c];
#pragma unroll
    for (int t = 0; t < 8; ++t)
      acc[t] += as_[(g * 8 + t) * HD + k] * wv;
  }
  float b = bm[c];
#pragma unroll
  for (int t = 0; t < 8; ++t) {
    int n = n0 + g * 8 + t;
    float v = acc[t] + b + feat[n * HID + c];
    feat[n * HID + c] = v;
    out[n * OUTW + outoff + c] = v;
  }
}

extern "C" void kernel_launch(void* const* d_in, const int* in_sizes, int n_in,
                              void* d_out, int out_size, void* d_ws, size_t ws_size,
                              hipStream_t stream) {
  const float* node_feat = (const float*)d_in[0];
  const float* edge_feat = (const float*)d_in[1];
  const int*   src       = (const int*)d_in[2];
  const int*   dst       = (const int*)d_in[3];
  const float* W_embed   = (const float*)d_in[4];
  const float* b_embed   = (const float*)d_in[5];
  const float* W_ni      = (const float*)d_in[6];
  const float* W_nj      = (const float*)d_in[7];
  const float* W_fij     = (const float*)d_in[8];
  const float* b_att     = (const float*)d_in[9];
  const float* attn      = (const float*)d_in[10];
  const float* W_node    = (const float*)d_in[11];
  const float* W_mlp     = (const float*)d_in[12];
  const float* b_mlp     = (const float*)d_in[13];
  float* out = (float*)d_out;

  // workspace layout
  float* ws   = (float*)d_ws;
  float* feat = ws;                                   // NN*HID f32
  u16*  fni   = (u16*)(feat + (size_t)NN * HID);      // NN*HD bf16
  u16*  fnj   = fni + (size_t)NN * HD;                // NN*HD bf16
  u16*  hn    = fnj + (size_t)NN * HD;                // NN*HD bf16
  u16*  efbp  = hn + (size_t)NN * HD;                 // NE*HID bf16 (CSR slot order)
  u16*  Wt    = efbp + (size_t)NE * HID;              // HD*HID bf16
  float* elog = (float*)(Wt + (size_t)HD * HID);      // HEADS*NE f32 (head-major)
  int* counts = (int*)(elog + (size_t)NE * HEADS);    // NN
  int* rowptr = counts + NN;                          // NN+1
  int* cursor = rowptr + NN + 1;                      // NN
  int* eidx   = cursor + NN;                          // NE
  int* srcp   = eidx + NE;                            // NE
  int* dstp   = srcp + NE;                            // NE
  float* aggb = (float*)fni;  // overlay fni+fnj; safe: written after edgelogits.

  hipMemsetAsync(counts, 0, sizeof(int) * NN, stream);
  hipMemsetAsync(cursor, 0, sizeof(int) * NN, stream);

  k_embed<<<(NN * 64) / 256, 256, 0, stream>>>(node_feat, W_embed, b_embed, feat, out);
  k_count<<<NE / 256, 256, 0, stream>>>(dst, counts);
  k_scan<<<1, 1024, 0, stream>>>(counts, rowptr);
  k_scatter<<<NE / 256, 256, 0, stream>>>(dst, src, rowptr, cursor, eidx, srcp, dstp);
  k_permute<<<(NE * 16) / 256, 256, 0, stream>>>(edge_feat, eidx, efbp);

  for (int L = 0; L < 2; ++L) {
    const float* WniL = W_ni + (size_t)L * HID * HD;
    const float* WnjL = W_nj + (size_t)L * HID * HD;
    const float* WfL  = W_fij + (size_t)L * HID * HD;
    const float* WndL = W_node + (size_t)L * HID * HD;
    const float* battL = b_att + (size_t)L * HD;
    const float* attnL = attn + (size_t)L * HEADS * HID;
    const float* WmL  = W_mlp + (size_t)L * HD * HID;
    const float* bmL  = b_mlp + (size_t)L * HID;

    k_prepw<<<(HID * HD) / 256, 256, 0, stream>>>(WfL, Wt);
    k_nodeproj<<<NN / 8, 256, 0, stream>>>(feat, WniL, WnjL, WndL, battL, fni, fnj, hn);
    k_edgelogits<<<2048, 256, 0, stream>>>(efbp, srcp, dstp, fni, fnj, Wt, attnL, elog);
    k_agg<<<(NN * 64) / 256, 256, 0, stream>>>(rowptr, srcp, elog, hn, aggb);
    k_mlp<<<NN / 32, 256, 0, stream>>>(aggb, WmL, bmL, feat, out, 80 + L * 64);
  }
}